// Round 1
// baseline (504.740 us; speedup 1.0000x reference)
//
#include <hip/hip_runtime.h>
#include <hip/hip_bf16.h>
#include <cstdint>
#include <cstddef>

#define T_TOK 8192
#define H_DIM 768
#define I_DIM 1024
#define N_EXP 5

typedef short v8s __attribute__((ext_vector_type(8)));
typedef float v4f __attribute__((ext_vector_type(4)));

static __device__ __forceinline__ unsigned short f2bf(float f) {
    union { float f; unsigned int u; } v; v.f = f;
    unsigned int u = v.u;
    unsigned int r = (u + 0x7fffu + ((u >> 16) & 1u)) >> 16;
    return (unsigned short)r;
}

// ---------------- x fp32 -> bf16 ----------------
__global__ void k_convert_x(const float* __restrict__ x, unsigned short* __restrict__ xb) {
    int i = (blockIdx.x * 256 + threadIdx.x) * 4;
    float4 v = *(const float4*)(x + i);
    ushort4 o;
    o.x = f2bf(v.x); o.y = f2bf(v.y); o.z = f2bf(v.z); o.w = f2bf(v.w);
    *(ushort4*)(xb + i) = o;
}

// ------------- transpose + convert weights: in [e][R][C] fp32 -> out [e][C][R] bf16 -------------
__global__ void k_transp(const float* __restrict__ a, const float* __restrict__ b,
                         unsigned short* __restrict__ at, unsigned short* __restrict__ bt,
                         int R, int C) {
    __shared__ float tile[32][33];
    int z = blockIdx.z;
    int e = z % N_EXP;
    const float* src = (z < N_EXP ? a : b) + (size_t)e * R * C;
    unsigned short* dst = (z < N_EXP ? at : bt) + (size_t)e * R * C;
    int c0 = blockIdx.x * 32, r0 = blockIdx.y * 32;
    int tx = threadIdx.x, ty = threadIdx.y;
#pragma unroll
    for (int i = 0; i < 4; i++)
        tile[ty * 4 + i][tx] = src[(size_t)(r0 + ty * 4 + i) * C + c0 + tx];
    __syncthreads();
#pragma unroll
    for (int i = 0; i < 4; i++)
        dst[(size_t)(c0 + ty * 4 + i) * R + r0 + tx] = f2bf(tile[tx][ty * 4 + i]);
}

// ---------------- router: top-2 of 5, renormalized ----------------
__global__ void k_router(const float* __restrict__ x, const float* __restrict__ rw,
                         const float* __restrict__ rb, int* __restrict__ cnt,
                         int* __restrict__ tokslot, float* __restrict__ pweight) {
    int t = blockIdx.x, lane = threadIdx.x;
    float acc[N_EXP];
#pragma unroll
    for (int e = 0; e < N_EXP; e++) acc[e] = 0.f;
    const float* xr = x + (size_t)t * H_DIM;
#pragma unroll
    for (int j = 0; j < H_DIM / 64; j++) {
        float xv = xr[lane + j * 64];
#pragma unroll
        for (int e = 0; e < N_EXP; e++) acc[e] += xv * rw[e * H_DIM + lane + j * 64];
    }
#pragma unroll
    for (int s = 32; s > 0; s >>= 1) {
#pragma unroll
        for (int e = 0; e < N_EXP; e++) acc[e] += __shfl_down(acc[e], s);
    }
    if (lane == 0) {
        float l[N_EXP];
#pragma unroll
        for (int e = 0; e < N_EXP; e++) l[e] = acc[e] + rb[e];
        int i1 = 0;
#pragma unroll
        for (int e = 1; e < N_EXP; e++) if (l[e] > l[i1]) i1 = e;
        int i2 = (i1 == 0) ? 1 : 0;
#pragma unroll
        for (int e = 0; e < N_EXP; e++) if (e != i1 && l[e] > l[i2]) i2 = e;
        // renormalized top-2 softmax == softmax over the two logits
        float w1 = 1.f / (1.f + __expf(l[i2] - l[i1]));
        float w2 = 1.f - w1;
        int p1 = atomicAdd(&cnt[i1], 1);
        tokslot[i1 * T_TOK + p1] = t; pweight[i1 * T_TOK + p1] = w1;
        int p2 = atomicAdd(&cnt[i2], 1);
        tokslot[i2 * T_TOK + p2] = t; pweight[i2 * T_TOK + p2] = w2;
    }
}

// ---------------- gate+up GEMM, SiLU*up*w epilogue -> hbuf (bf16) ----------------
__launch_bounds__(256, 2)
__global__ void k_gateup(const unsigned short* __restrict__ xb,
                         const unsigned short* __restrict__ gbt,
                         const unsigned short* __restrict__ ubt,
                         const int* __restrict__ cnt,
                         const int* __restrict__ tokslot,
                         const float* __restrict__ pweight,
                         unsigned short* __restrict__ hbuf) {
    const int e = blockIdx.z;
    const int cn = cnt[e];
    const int m0 = blockIdx.x * 64;
    if (m0 >= cn) return;
    int off = 0;
    for (int i = 0; i < e; i++) off += cnt[i];
    const int n0 = blockIdx.y * 64;

    __shared__ __align__(16) unsigned short ldsA[64 * 40];
    __shared__ __align__(16) unsigned short ldsBg[64 * 40];
    __shared__ __align__(16) unsigned short ldsBu[64 * 40];
    __shared__ int tokLds[64];
    __shared__ float pwLds[64];

    const int tid = threadIdx.x;
    if (tid < 64) {
        int gr = m0 + tid;
        int tk = 0; float pw = 0.f;
        if (gr < cn) { tk = tokslot[e * T_TOK + gr]; pw = pweight[e * T_TOK + gr]; }
        tokLds[tid] = tk; pwLds[tid] = pw;
    }
    __syncthreads();

    const int lane = tid & 63;
    const int w = tid >> 6;
    const int wm = (w & 1) * 32, wn = (w >> 1) * 32;
    const int fm = lane & 15, quad = lane >> 4;

    v4f accg[2][2], accu[2][2];
#pragma unroll
    for (int i = 0; i < 2; i++)
#pragma unroll
        for (int j = 0; j < 2; j++) { accg[i][j] = (v4f)0.f; accu[i][j] = (v4f)0.f; }

    const int sr = tid >> 2;        // 0..63 staged row
    const int sc = (tid & 3) * 8;   // bf16 col offset within BK=32
    const int tkR = tokLds[sr];
    const size_t aBase = (size_t)tkR * H_DIM + sc;
    const size_t bBase = ((size_t)e * I_DIM + n0 + sr) * H_DIM + sc;

    for (int kb = 0; kb < H_DIM / 32; kb++) {
        int k0 = kb * 32;
        uint4 av = *(const uint4*)(xb + aBase + k0);
        uint4 gv = *(const uint4*)(gbt + bBase + k0);
        uint4 uv = *(const uint4*)(ubt + bBase + k0);
        *(uint4*)&ldsA[sr * 40 + sc] = av;
        *(uint4*)&ldsBg[sr * 40 + sc] = gv;
        *(uint4*)&ldsBu[sr * 40 + sc] = uv;
        __syncthreads();
        v8s aF[2], bgF[2], buF[2];
#pragma unroll
        for (int im = 0; im < 2; im++)
            aF[im] = *(const v8s*)&ldsA[(wm + im * 16 + fm) * 40 + quad * 8];
#pragma unroll
        for (int in = 0; in < 2; in++) {
            bgF[in] = *(const v8s*)&ldsBg[(wn + in * 16 + fm) * 40 + quad * 8];
            buF[in] = *(const v8s*)&ldsBu[(wn + in * 16 + fm) * 40 + quad * 8];
        }
#pragma unroll
        for (int im = 0; im < 2; im++)
#pragma unroll
            for (int in = 0; in < 2; in++) {
                accg[im][in] = __builtin_amdgcn_mfma_f32_16x16x32_bf16(aF[im], bgF[in], accg[im][in], 0, 0, 0);
                accu[im][in] = __builtin_amdgcn_mfma_f32_16x16x32_bf16(aF[im], buF[in], accu[im][in], 0, 0, 0);
            }
        __syncthreads();
    }

#pragma unroll
    for (int im = 0; im < 2; im++) {
#pragma unroll
        for (int reg = 0; reg < 4; reg++) {
            int lr = wm + im * 16 + quad * 4 + reg;
            int gr = m0 + lr;
            if (gr < cn) {
                float pw = pwLds[lr];
#pragma unroll
                for (int in = 0; in < 2; in++) {
                    float g = accg[im][in][reg];
                    float u = accu[im][in][reg];
                    float s = g / (1.f + __expf(-g));
                    int col = n0 + wn + in * 16 + fm;
                    hbuf[(size_t)(off + gr) * I_DIM + col] = f2bf(s * u * pw);
                }
            }
        }
    }
}

// ---------------- down GEMM, scatter-add into out ----------------
__launch_bounds__(256, 2)
__global__ void k_down(const unsigned short* __restrict__ hbuf,
                       const unsigned short* __restrict__ dbt,
                       const int* __restrict__ cnt,
                       const int* __restrict__ tokslot,
                       float* __restrict__ out) {
    const int e = blockIdx.z;
    const int cn = cnt[e];
    const int m0 = blockIdx.x * 64;
    if (m0 >= cn) return;
    int off = 0;
    for (int i = 0; i < e; i++) off += cnt[i];
    const int n0 = blockIdx.y * 64;

    __shared__ __align__(16) unsigned short ldsA[64 * 40];
    __shared__ __align__(16) unsigned short ldsB[64 * 40];
    __shared__ int tokLds[64];

    const int tid = threadIdx.x;
    if (tid < 64) {
        int gr = m0 + tid;
        tokLds[tid] = (gr < cn) ? tokslot[e * T_TOK + gr] : 0;
    }
    __syncthreads();

    const int lane = tid & 63;
    const int w = tid >> 6;
    const int wm = (w & 1) * 32, wn = (w >> 1) * 32;
    const int fm = lane & 15, quad = lane >> 4;

    v4f acc[2][2];
#pragma unroll
    for (int i = 0; i < 2; i++)
#pragma unroll
        for (int j = 0; j < 2; j++) acc[i][j] = (v4f)0.f;

    const int sr = tid >> 2;
    const int sc = (tid & 3) * 8;
    int arow = m0 + sr; if (arow >= cn) arow = cn - 1;
    const size_t aBase = (size_t)(off + arow) * I_DIM + sc;
    const size_t bBase = ((size_t)e * H_DIM + n0 + sr) * I_DIM + sc;

    for (int kb = 0; kb < I_DIM / 32; kb++) {
        int k0 = kb * 32;
        uint4 av = *(const uint4*)(hbuf + aBase + k0);
        uint4 bv = *(const uint4*)(dbt + bBase + k0);
        *(uint4*)&ldsA[sr * 40 + sc] = av;
        *(uint4*)&ldsB[sr * 40 + sc] = bv;
        __syncthreads();
        v8s aF[2], bF[2];
#pragma unroll
        for (int im = 0; im < 2; im++)
            aF[im] = *(const v8s*)&ldsA[(wm + im * 16 + fm) * 40 + quad * 8];
#pragma unroll
        for (int in = 0; in < 2; in++)
            bF[in] = *(const v8s*)&ldsB[(wn + in * 16 + fm) * 40 + quad * 8];
#pragma unroll
        for (int im = 0; im < 2; im++)
#pragma unroll
            for (int in = 0; in < 2; in++)
                acc[im][in] = __builtin_amdgcn_mfma_f32_16x16x32_bf16(aF[im], bF[in], acc[im][in], 0, 0, 0);
        __syncthreads();
    }

#pragma unroll
    for (int im = 0; im < 2; im++) {
#pragma unroll
        for (int reg = 0; reg < 4; reg++) {
            int lr = wm + im * 16 + quad * 4 + reg;
            int gr = m0 + lr;
            if (gr < cn) {
                int tok = tokLds[lr];
#pragma unroll
                for (int in = 0; in < 2; in++) {
                    int col = n0 + wn + in * 16 + fm;
                    atomicAdd(&out[(size_t)tok * H_DIM + col], acc[im][in][reg]);
                }
            }
        }
    }
}

extern "C" void kernel_launch(void* const* d_in, const int* in_sizes, int n_in,
                              void* d_out, int out_size, void* d_ws, size_t ws_size,
                              hipStream_t stream) {
    const float* x  = (const float*)d_in[0];
    const float* rw = (const float*)d_in[1];
    const float* rb = (const float*)d_in[2];
    const float* gw = (const float*)d_in[3];
    const float* uw = (const float*)d_in[4];
    const float* dw = (const float*)d_in[5];
    float* out = (float*)d_out;

    char* ws = (char*)d_ws;
    size_t o = 0;
    auto alloc = [&](size_t bytes) { void* p = ws + o; o += (bytes + 255) & ~255ull; return p; };
    int*   cnt     = (int*)  alloc(N_EXP * 4);
    int*   tokslot = (int*)  alloc((size_t)N_EXP * T_TOK * 4);
    float* pweight = (float*)alloc((size_t)N_EXP * T_TOK * 4);
    unsigned short* xb   = (unsigned short*)alloc((size_t)T_TOK * H_DIM * 2);
    unsigned short* gbt  = (unsigned short*)alloc((size_t)N_EXP * H_DIM * I_DIM * 2);
    unsigned short* ubt  = (unsigned short*)alloc((size_t)N_EXP * H_DIM * I_DIM * 2);
    unsigned short* dbt  = (unsigned short*)alloc((size_t)N_EXP * H_DIM * I_DIM * 2);
    unsigned short* hbuf = (unsigned short*)alloc((size_t)2 * T_TOK * I_DIM * 2);

    hipMemsetAsync(cnt, 0, N_EXP * 4, stream);
    hipMemsetAsync(d_out, 0, (size_t)out_size * 4, stream);

    k_convert_x<<<T_TOK * H_DIM / 1024, 256, 0, stream>>>(x, xb);

    dim3 tg1(I_DIM / 32, H_DIM / 32, 2 * N_EXP);
    k_transp<<<tg1, dim3(32, 8), 0, stream>>>(gw, uw, gbt, ubt, H_DIM, I_DIM);
    dim3 tg2(H_DIM / 32, I_DIM / 32, N_EXP);
    k_transp<<<tg2, dim3(32, 8), 0, stream>>>(dw, dw, dbt, dbt, I_DIM, H_DIM);

    k_router<<<T_TOK, 64, 0, stream>>>(x, rw, rb, cnt, tokslot, pweight);

    dim3 g1(T_TOK / 64, I_DIM / 64, N_EXP);
    k_gateup<<<g1, 256, 0, stream>>>(xb, gbt, ubt, cnt, tokslot, pweight, hbuf);

    dim3 g2(T_TOK / 64, H_DIM / 64, N_EXP);
    k_down<<<g2, 256, 0, stream>>>(hbuf, dbt, cnt, tokslot, out);
}

// Round 2
// 315.939 us; speedup vs baseline: 1.5976x; 1.5976x over previous
//
#include <hip/hip_runtime.h>
#include <hip/hip_bf16.h>
#include <cstdint>
#include <cstddef>

#define T_TOK 8192
#define H_DIM 768
#define I_DIM 1024
#define N_EXP 5

typedef short v8s __attribute__((ext_vector_type(8)));
typedef float v4f __attribute__((ext_vector_type(4)));

static __device__ __forceinline__ unsigned short f2bf(float f) {
    union { float f; unsigned int u; } v; v.f = f;
    unsigned int u = v.u;
    unsigned int r = (u + 0x7fffu + ((u >> 16) & 1u)) >> 16;
    return (unsigned short)r;
}

// ------------- transpose + convert weights: in [e][R][C] fp32 -> out [e][C][R] bf16 -------------
__global__ void k_transp(const float* __restrict__ a, const float* __restrict__ b,
                         unsigned short* __restrict__ at, unsigned short* __restrict__ bt,
                         int R, int C) {
    __shared__ float tile[32][33];
    int z = blockIdx.z;
    int e = z % N_EXP;
    const float* src = (z < N_EXP ? a : b) + (size_t)e * R * C;
    unsigned short* dst = (z < N_EXP ? at : bt) + (size_t)e * R * C;
    int c0 = blockIdx.x * 32, r0 = blockIdx.y * 32;
    int tx = threadIdx.x, ty = threadIdx.y;
#pragma unroll
    for (int i = 0; i < 4; i++)
        tile[ty * 4 + i][tx] = src[(size_t)(r0 + ty * 4 + i) * C + c0 + tx];
    __syncthreads();
#pragma unroll
    for (int i = 0; i < 4; i++)
        dst[(size_t)(c0 + ty * 4 + i) * R + r0 + tx] = f2bf(tile[tx][ty * 4 + i]);
}

// ---------------- router phase A: logits + top2 + fused x->bf16 convert ----------------
// one wave per token; 4 waves per block
__global__ void k_router_a(const float* __restrict__ x, const float* __restrict__ rw,
                           const float* __restrict__ rb,
                           unsigned short* __restrict__ xb,
                           int* __restrict__ top2e, float2* __restrict__ top2w) {
    const int wave = threadIdx.x >> 6, lane = threadIdx.x & 63;
    const int t = blockIdx.x * 4 + wave;
    const float* xr = x + (size_t)t * H_DIM;
    unsigned short* xbr = xb + (size_t)t * H_DIM;
    float acc[N_EXP];
#pragma unroll
    for (int e = 0; e < N_EXP; e++) acc[e] = 0.f;
#pragma unroll
    for (int j = 0; j < H_DIM / 256; j++) {
        int idx = j * 256 + lane * 4;
        float4 xv = *(const float4*)(xr + idx);
        ushort4 o;
        o.x = f2bf(xv.x); o.y = f2bf(xv.y); o.z = f2bf(xv.z); o.w = f2bf(xv.w);
        *(ushort4*)(xbr + idx) = o;
#pragma unroll
        for (int e = 0; e < N_EXP; e++) {
            float4 wv = *(const float4*)(rw + e * H_DIM + idx);
            acc[e] += xv.x * wv.x + xv.y * wv.y + xv.z * wv.z + xv.w * wv.w;
        }
    }
#pragma unroll
    for (int s = 32; s > 0; s >>= 1) {
#pragma unroll
        for (int e = 0; e < N_EXP; e++) acc[e] += __shfl_down(acc[e], s);
    }
    if (lane == 0) {
        float l[N_EXP];
#pragma unroll
        for (int e = 0; e < N_EXP; e++) l[e] = acc[e] + rb[e];
        int i1 = 0;
#pragma unroll
        for (int e = 1; e < N_EXP; e++) if (l[e] > l[i1]) i1 = e;
        int i2 = (i1 == 0) ? 1 : 0;
#pragma unroll
        for (int e = 0; e < N_EXP; e++) if (e != i1 && l[e] > l[i2]) i2 = e;
        // renormalized top-2 softmax == softmax over the two logits
        float w1 = 1.f / (1.f + __expf(l[i2] - l[i1]));
        top2e[t] = i1 | (i2 << 8);
        top2w[t] = make_float2(w1, 1.f - w1);
    }
}

// ---------------- router phase B: block-aggregated list build ----------------
__global__ void k_router_b(const int* __restrict__ top2e, const float2* __restrict__ top2w,
                           int* __restrict__ cnt, int* __restrict__ tokslot,
                           float* __restrict__ pweight) {
    __shared__ int lcnt[N_EXP], lbase[N_EXP];
    const int tid = threadIdx.x;
    if (tid < N_EXP) lcnt[tid] = 0;
    __syncthreads();
    const int t = blockIdx.x * 256 + tid;
    const int pe = top2e[t];
    const float2 wv = top2w[t];
    const int e1 = pe & 0xff, e2 = pe >> 8;
    const int s1 = atomicAdd(&lcnt[e1], 1);
    const int s2 = atomicAdd(&lcnt[e2], 1);
    __syncthreads();
    if (tid < N_EXP) lbase[tid] = atomicAdd(&cnt[tid], lcnt[tid]);
    __syncthreads();
    const int p1 = lbase[e1] + s1;
    tokslot[e1 * T_TOK + p1] = t; pweight[e1 * T_TOK + p1] = wv.x;
    const int p2 = lbase[e2] + s2;
    tokslot[e2 * T_TOK + p2] = t; pweight[e2 * T_TOK + p2] = wv.y;
}

// ---------------- gate+up GEMM, SiLU*up*w epilogue -> hbuf (bf16) ----------------
__launch_bounds__(256, 2)
__global__ void k_gateup(const unsigned short* __restrict__ xb,
                         const unsigned short* __restrict__ gbt,
                         const unsigned short* __restrict__ ubt,
                         const int* __restrict__ cnt,
                         const int* __restrict__ tokslot,
                         const float* __restrict__ pweight,
                         unsigned short* __restrict__ hbuf) {
    const int e = blockIdx.z;
    const int cn = cnt[e];
    const int m0 = blockIdx.x * 64;
    if (m0 >= cn) return;
    int off = 0;
    for (int i = 0; i < e; i++) off += cnt[i];
    const int n0 = blockIdx.y * 64;

    __shared__ __align__(16) unsigned short ldsA[64 * 40];
    __shared__ __align__(16) unsigned short ldsBg[64 * 40];
    __shared__ __align__(16) unsigned short ldsBu[64 * 40];
    __shared__ int tokLds[64];
    __shared__ float pwLds[64];

    const int tid = threadIdx.x;
    if (tid < 64) {
        int gr = m0 + tid;
        int tk = 0; float pw = 0.f;
        if (gr < cn) { tk = tokslot[e * T_TOK + gr]; pw = pweight[e * T_TOK + gr]; }
        tokLds[tid] = tk; pwLds[tid] = pw;
    }
    __syncthreads();

    const int lane = tid & 63;
    const int w = tid >> 6;
    const int wm = (w & 1) * 32, wn = (w >> 1) * 32;
    const int fm = lane & 15, quad = lane >> 4;

    v4f accg[2][2], accu[2][2];
#pragma unroll
    for (int i = 0; i < 2; i++)
#pragma unroll
        for (int j = 0; j < 2; j++) { accg[i][j] = (v4f)0.f; accu[i][j] = (v4f)0.f; }

    const int sr = tid >> 2;        // 0..63 staged row
    const int sc = (tid & 3) * 8;   // bf16 col offset within BK=32
    const int tkR = tokLds[sr];
    const size_t aBase = (size_t)tkR * H_DIM + sc;
    const size_t bBase = ((size_t)e * I_DIM + n0 + sr) * H_DIM + sc;

    for (int kb = 0; kb < H_DIM / 32; kb++) {
        int k0 = kb * 32;
        uint4 av = *(const uint4*)(xb + aBase + k0);
        uint4 gv = *(const uint4*)(gbt + bBase + k0);
        uint4 uv = *(const uint4*)(ubt + bBase + k0);
        *(uint4*)&ldsA[sr * 40 + sc] = av;
        *(uint4*)&ldsBg[sr * 40 + sc] = gv;
        *(uint4*)&ldsBu[sr * 40 + sc] = uv;
        __syncthreads();
        v8s aF[2], bgF[2], buF[2];
#pragma unroll
        for (int im = 0; im < 2; im++)
            aF[im] = *(const v8s*)&ldsA[(wm + im * 16 + fm) * 40 + quad * 8];
#pragma unroll
        for (int in = 0; in < 2; in++) {
            bgF[in] = *(const v8s*)&ldsBg[(wn + in * 16 + fm) * 40 + quad * 8];
            buF[in] = *(const v8s*)&ldsBu[(wn + in * 16 + fm) * 40 + quad * 8];
        }
#pragma unroll
        for (int im = 0; im < 2; im++)
#pragma unroll
            for (int in = 0; in < 2; in++) {
                accg[im][in] = __builtin_amdgcn_mfma_f32_16x16x32_bf16(aF[im], bgF[in], accg[im][in], 0, 0, 0);
                accu[im][in] = __builtin_amdgcn_mfma_f32_16x16x32_bf16(aF[im], buF[in], accu[im][in], 0, 0, 0);
            }
        __syncthreads();
    }

#pragma unroll
    for (int im = 0; im < 2; im++) {
#pragma unroll
        for (int reg = 0; reg < 4; reg++) {
            int lr = wm + im * 16 + quad * 4 + reg;
            int gr = m0 + lr;
            if (gr < cn) {
                float pw = pwLds[lr];
#pragma unroll
                for (int in = 0; in < 2; in++) {
                    float g = accg[im][in][reg];
                    float u = accu[im][in][reg];
                    float s = g / (1.f + __expf(-g));
                    int col = n0 + wn + in * 16 + fm;
                    hbuf[(size_t)(off + gr) * I_DIM + col] = f2bf(s * u * pw);
                }
            }
        }
    }
}

// ---------------- down GEMM, scatter-add into out ----------------
__launch_bounds__(256, 2)
__global__ void k_down(const unsigned short* __restrict__ hbuf,
                       const unsigned short* __restrict__ dbt,
                       const int* __restrict__ cnt,
                       const int* __restrict__ tokslot,
                       float* __restrict__ out) {
    const int e = blockIdx.z;
    const int cn = cnt[e];
    const int m0 = blockIdx.x * 64;
    if (m0 >= cn) return;
    int off = 0;
    for (int i = 0; i < e; i++) off += cnt[i];
    const int n0 = blockIdx.y * 64;

    __shared__ __align__(16) unsigned short ldsA[64 * 40];
    __shared__ __align__(16) unsigned short ldsB[64 * 40];
    __shared__ int tokLds[64];

    const int tid = threadIdx.x;
    if (tid < 64) {
        int gr = m0 + tid;
        tokLds[tid] = (gr < cn) ? tokslot[e * T_TOK + gr] : 0;
    }
    __syncthreads();

    const int lane = tid & 63;
    const int w = tid >> 6;
    const int wm = (w & 1) * 32, wn = (w >> 1) * 32;
    const int fm = lane & 15, quad = lane >> 4;

    v4f acc[2][2];
#pragma unroll
    for (int i = 0; i < 2; i++)
#pragma unroll
        for (int j = 0; j < 2; j++) acc[i][j] = (v4f)0.f;

    const int sr = tid >> 2;
    const int sc = (tid & 3) * 8;
    int arow = m0 + sr; if (arow >= cn) arow = cn - 1;
    const size_t aBase = (size_t)(off + arow) * I_DIM + sc;
    const size_t bBase = ((size_t)e * H_DIM + n0 + sr) * I_DIM + sc;

    for (int kb = 0; kb < I_DIM / 32; kb++) {
        int k0 = kb * 32;
        uint4 av = *(const uint4*)(hbuf + aBase + k0);
        uint4 bv = *(const uint4*)(dbt + bBase + k0);
        *(uint4*)&ldsA[sr * 40 + sc] = av;
        *(uint4*)&ldsB[sr * 40 + sc] = bv;
        __syncthreads();
        v8s aF[2], bF[2];
#pragma unroll
        for (int im = 0; im < 2; im++)
            aF[im] = *(const v8s*)&ldsA[(wm + im * 16 + fm) * 40 + quad * 8];
#pragma unroll
        for (int in = 0; in < 2; in++)
            bF[in] = *(const v8s*)&ldsB[(wn + in * 16 + fm) * 40 + quad * 8];
#pragma unroll
        for (int im = 0; im < 2; im++)
#pragma unroll
            for (int in = 0; in < 2; in++)
                acc[im][in] = __builtin_amdgcn_mfma_f32_16x16x32_bf16(aF[im], bF[in], acc[im][in], 0, 0, 0);
        __syncthreads();
    }

#pragma unroll
    for (int im = 0; im < 2; im++) {
#pragma unroll
        for (int reg = 0; reg < 4; reg++) {
            int lr = wm + im * 16 + quad * 4 + reg;
            int gr = m0 + lr;
            if (gr < cn) {
                int tok = tokLds[lr];
#pragma unroll
                for (int in = 0; in < 2; in++) {
                    int col = n0 + wn + in * 16 + fm;
                    atomicAdd(&out[(size_t)tok * H_DIM + col], acc[im][in][reg]);
                }
            }
        }
    }
}

extern "C" void kernel_launch(void* const* d_in, const int* in_sizes, int n_in,
                              void* d_out, int out_size, void* d_ws, size_t ws_size,
                              hipStream_t stream) {
    const float* x  = (const float*)d_in[0];
    const float* rw = (const float*)d_in[1];
    const float* rb = (const float*)d_in[2];
    const float* gw = (const float*)d_in[3];
    const float* uw = (const float*)d_in[4];
    const float* dw = (const float*)d_in[5];
    float* out = (float*)d_out;

    char* ws = (char*)d_ws;
    size_t o = 0;
    auto alloc = [&](size_t bytes) { void* p = ws + o; o += (bytes + 255) & ~255ull; return p; };
    int*   cnt     = (int*)  alloc(N_EXP * 4);
    int*   tokslot = (int*)  alloc((size_t)N_EXP * T_TOK * 4);
    float* pweight = (float*)alloc((size_t)N_EXP * T_TOK * 4);
    int*   top2e   = (int*)  alloc((size_t)T_TOK * 4);
    float2* top2w  = (float2*)alloc((size_t)T_TOK * 8);
    unsigned short* xb   = (unsigned short*)alloc((size_t)T_TOK * H_DIM * 2);
    unsigned short* gbt  = (unsigned short*)alloc((size_t)N_EXP * H_DIM * I_DIM * 2);
    unsigned short* ubt  = (unsigned short*)alloc((size_t)N_EXP * H_DIM * I_DIM * 2);
    unsigned short* dbt  = (unsigned short*)alloc((size_t)N_EXP * H_DIM * I_DIM * 2);
    unsigned short* hbuf = (unsigned short*)alloc((size_t)2 * T_TOK * I_DIM * 2);

    hipMemsetAsync(cnt, 0, N_EXP * 4, stream);
    hipMemsetAsync(d_out, 0, (size_t)out_size * 4, stream);

    dim3 tg1(I_DIM / 32, H_DIM / 32, 2 * N_EXP);
    k_transp<<<tg1, dim3(32, 8), 0, stream>>>(gw, uw, gbt, ubt, H_DIM, I_DIM);
    dim3 tg2(H_DIM / 32, I_DIM / 32, N_EXP);
    k_transp<<<tg2, dim3(32, 8), 0, stream>>>(dw, dw, dbt, dbt, I_DIM, H_DIM);

    k_router_a<<<T_TOK / 4, 256, 0, stream>>>(x, rw, rb, xb, top2e, top2w);
    k_router_b<<<T_TOK / 256, 256, 0, stream>>>(top2e, top2w, cnt, tokslot, pweight);

    dim3 g1(T_TOK / 64, I_DIM / 64, N_EXP);
    k_gateup<<<g1, 256, 0, stream>>>(xb, gbt, ubt, cnt, tokslot, pweight, hbuf);

    dim3 g2(T_TOK / 64, H_DIM / 64, N_EXP);
    k_down<<<g2, 256, 0, stream>>>(hbuf, dbt, cnt, tokslot, out);
}

// Round 3
// 286.118 us; speedup vs baseline: 1.7641x; 1.1042x over previous
//
#include <hip/hip_runtime.h>
#include <hip/hip_bf16.h>
#include <cstdint>
#include <cstddef>

#define T_TOK 8192
#define H_DIM 768
#define I_DIM 1024
#define N_EXP 5

typedef short v8s __attribute__((ext_vector_type(8)));
typedef float v4f __attribute__((ext_vector_type(4)));

static __device__ __forceinline__ unsigned short f2bf(float f) {
    union { float f; unsigned int u; } v; v.f = f;
    unsigned int u = v.u;
    unsigned int r = (u + 0x7fffu + ((u >> 16) & 1u)) >> 16;
    return (unsigned short)r;
}

// async 16B global->LDS (wave-uniform LDS base + lane*16; per-lane global addr OK)
static __device__ __forceinline__ void async16(const unsigned short* g, unsigned short* l) {
    __builtin_amdgcn_global_load_lds(
        (const __attribute__((address_space(1))) unsigned int*)g,
        (__attribute__((address_space(3))) unsigned int*)l, 16, 0, 0);
}

// ------------- transpose + convert weights: in [e][R][C] fp32 -> out [e][C][R] bf16 -------------
__global__ void k_transp(const float* __restrict__ a, const float* __restrict__ b,
                         unsigned short* __restrict__ at, unsigned short* __restrict__ bt,
                         int R, int C) {
    __shared__ float tile[32][33];
    int z = blockIdx.z;
    int e = z % N_EXP;
    const float* src = (z < N_EXP ? a : b) + (size_t)e * R * C;
    unsigned short* dst = (z < N_EXP ? at : bt) + (size_t)e * R * C;
    int c0 = blockIdx.x * 32, r0 = blockIdx.y * 32;
    int tx = threadIdx.x, ty = threadIdx.y;
#pragma unroll
    for (int i = 0; i < 4; i++)
        tile[ty * 4 + i][tx] = src[(size_t)(r0 + ty * 4 + i) * C + c0 + tx];
    __syncthreads();
#pragma unroll
    for (int i = 0; i < 4; i++)
        dst[(size_t)(c0 + ty * 4 + i) * R + r0 + tx] = f2bf(tile[tx][ty * 4 + i]);
}

// ---------------- router phase A: logits + top2 + fused x->bf16 convert ----------------
__global__ void k_router_a(const float* __restrict__ x, const float* __restrict__ rw,
                           const float* __restrict__ rb,
                           unsigned short* __restrict__ xb,
                           int* __restrict__ top2e, float2* __restrict__ top2w) {
    const int wave = threadIdx.x >> 6, lane = threadIdx.x & 63;
    const int t = blockIdx.x * 4 + wave;
    const float* xr = x + (size_t)t * H_DIM;
    unsigned short* xbr = xb + (size_t)t * H_DIM;
    float acc[N_EXP];
#pragma unroll
    for (int e = 0; e < N_EXP; e++) acc[e] = 0.f;
#pragma unroll
    for (int j = 0; j < H_DIM / 256; j++) {
        int idx = j * 256 + lane * 4;
        float4 xv = *(const float4*)(xr + idx);
        ushort4 o;
        o.x = f2bf(xv.x); o.y = f2bf(xv.y); o.z = f2bf(xv.z); o.w = f2bf(xv.w);
        *(ushort4*)(xbr + idx) = o;
#pragma unroll
        for (int e = 0; e < N_EXP; e++) {
            float4 wv = *(const float4*)(rw + e * H_DIM + idx);
            acc[e] += xv.x * wv.x + xv.y * wv.y + xv.z * wv.z + xv.w * wv.w;
        }
    }
#pragma unroll
    for (int s = 32; s > 0; s >>= 1) {
#pragma unroll
        for (int e = 0; e < N_EXP; e++) acc[e] += __shfl_down(acc[e], s);
    }
    if (lane == 0) {
        float l[N_EXP];
#pragma unroll
        for (int e = 0; e < N_EXP; e++) l[e] = acc[e] + rb[e];
        int i1 = 0;
#pragma unroll
        for (int e = 1; e < N_EXP; e++) if (l[e] > l[i1]) i1 = e;
        int i2 = (i1 == 0) ? 1 : 0;
#pragma unroll
        for (int e = 0; e < N_EXP; e++) if (e != i1 && l[e] > l[i2]) i2 = e;
        float w1 = 1.f / (1.f + __expf(l[i2] - l[i1]));
        top2e[t] = i1 | (i2 << 8);
        top2w[t] = make_float2(w1, 1.f - w1);
    }
}

// ---------------- router phase B: block-aggregated list build ----------------
__global__ void k_router_b(const int* __restrict__ top2e, const float2* __restrict__ top2w,
                           int* __restrict__ cnt, int* __restrict__ tokslot,
                           float* __restrict__ pweight) {
    __shared__ int lcnt[N_EXP], lbase[N_EXP];
    const int tid = threadIdx.x;
    if (tid < N_EXP) lcnt[tid] = 0;
    __syncthreads();
    const int t = blockIdx.x * 256 + tid;
    const int pe = top2e[t];
    const float2 wv = top2w[t];
    const int e1 = pe & 0xff, e2 = pe >> 8;
    const int s1 = atomicAdd(&lcnt[e1], 1);
    const int s2 = atomicAdd(&lcnt[e2], 1);
    __syncthreads();
    if (tid < N_EXP) lbase[tid] = atomicAdd(&cnt[tid], lcnt[tid]);
    __syncthreads();
    const int p1 = lbase[e1] + s1;
    tokslot[e1 * T_TOK + p1] = t; pweight[e1 * T_TOK + p1] = wv.x;
    const int p2 = lbase[e2] + s2;
    tokslot[e2 * T_TOK + p2] = t; pweight[e2 * T_TOK + p2] = wv.y;
}

// ---------------- gate+up fused GEMM (m97-style), SiLU*up*w epilogue -> hbuf ----------------
// Tile: 128 tokens x 64 I-cols; B-eff = [64 gate rows; 64 up rows] -> 128x128 MFMA tile.
// Wave w computes A-rows [w*32, w*32+32) x all 128 eff-cols: acc[2][8].
// g and u for the same output element are in the same lane: acc[im][in] / acc[im][in+4].
__launch_bounds__(256, 2)
__global__ void k_gateup(const unsigned short* __restrict__ xb,
                         const unsigned short* __restrict__ gbt,
                         const unsigned short* __restrict__ ubt,
                         const int* __restrict__ cnt,
                         const int* __restrict__ tokslot,
                         const float* __restrict__ pweight,
                         unsigned short* __restrict__ hbuf) {
    const int e = blockIdx.z;
    const int cn = cnt[e];
    const int m0 = blockIdx.x * 128;
    if (m0 >= cn) return;
    int off = 0;
    for (int i = 0; i < e; i++) off += cnt[i];
    const int n0 = blockIdx.y * 64;

    __shared__ __align__(16) unsigned short ldsA[128 * 32];
    __shared__ __align__(16) unsigned short ldsB[128 * 32];
    __shared__ int tokLds[128];
    __shared__ float pwLds[128];

    const int tid = threadIdx.x;
    if (tid < 128) {
        int gr = m0 + tid;
        int tk = 0; float pw = 0.f;
        if (gr < cn) { tk = tokslot[e * T_TOK + gr]; pw = pweight[e * T_TOK + gr]; }
        tokLds[tid] = tk; pwLds[tid] = pw;
    }
    __syncthreads();

    const int lane = tid & 63;
    const int wave = tid >> 6;
    const int fm = lane & 15, quad = lane >> 4;

    // staging: each wave fills 16 consecutive 64B rows per call (lane l -> row base+l/4, col (l&3)*8)
    const int srow = wave * 16 + (lane >> 2);   // 0..63
    const int scol = (lane & 3) * 8;
    const unsigned short* aG1 = xb + (size_t)tokLds[srow] * H_DIM + scol;
    const unsigned short* aG2 = xb + (size_t)tokLds[64 + srow] * H_DIM + scol;
    const unsigned short* bG1 = gbt + ((size_t)e * I_DIM + n0 + srow) * H_DIM + scol;
    const unsigned short* bG2 = ubt + ((size_t)e * I_DIM + n0 + srow) * H_DIM + scol;
    unsigned short* lA1 = ldsA + wave * 512;
    unsigned short* lA2 = ldsA + 2048 + wave * 512;
    unsigned short* lB1 = ldsB + wave * 512;
    unsigned short* lB2 = ldsB + 2048 + wave * 512;

    const int wm = wave * 32;

    v4f acc[2][8];
#pragma unroll
    for (int i = 0; i < 2; i++)
#pragma unroll
        for (int j = 0; j < 8; j++) acc[i][j] = (v4f)0.f;

    for (int kb = 0; kb < H_DIM / 32; kb++) {
        const int k0 = kb * 32;
        async16(aG1 + k0, lA1);
        async16(aG2 + k0, lA2);
        async16(bG1 + k0, lB1);
        async16(bG2 + k0, lB2);
        __syncthreads();
        v8s aF[2], bF[8];
#pragma unroll
        for (int im = 0; im < 2; im++)
            aF[im] = *(const v8s*)&ldsA[(wm + im * 16 + fm) * 32 + quad * 8];
#pragma unroll
        for (int in = 0; in < 8; in++)
            bF[in] = *(const v8s*)&ldsB[(in * 16 + fm) * 32 + quad * 8];
#pragma unroll
        for (int im = 0; im < 2; im++)
#pragma unroll
            for (int in = 0; in < 8; in++)
                acc[im][in] = __builtin_amdgcn_mfma_f32_16x16x32_bf16(aF[im], bF[in], acc[im][in], 0, 0, 0);
        __syncthreads();
    }

#pragma unroll
    for (int im = 0; im < 2; im++) {
#pragma unroll
        for (int reg = 0; reg < 4; reg++) {
            int lr = wm + im * 16 + quad * 4 + reg;
            int gr = m0 + lr;
            if (gr < cn) {
                float pw = pwLds[lr];
                size_t base = (size_t)(off + gr) * I_DIM + n0 + fm;
#pragma unroll
                for (int in = 0; in < 4; in++) {
                    float g = acc[im][in][reg];
                    float u = acc[im][in + 4][reg];
                    float s = g / (1.f + __expf(-g));
                    hbuf[base + in * 16] = f2bf(s * u * pw);
                }
            }
        }
    }
}

// ---------------- down GEMM (m97-style 128x128), scatter-add into out ----------------
__launch_bounds__(256, 2)
__global__ void k_down(const unsigned short* __restrict__ hbuf,
                       const unsigned short* __restrict__ dbt,
                       const int* __restrict__ cnt,
                       const int* __restrict__ tokslot,
                       float* __restrict__ out) {
    const int e = blockIdx.z;
    const int cn = cnt[e];
    const int m0 = blockIdx.x * 128;
    if (m0 >= cn) return;
    int off = 0;
    for (int i = 0; i < e; i++) off += cnt[i];
    const int n0 = blockIdx.y * 128;

    __shared__ __align__(16) unsigned short ldsA[128 * 32];
    __shared__ __align__(16) unsigned short ldsB[128 * 32];
    __shared__ int tokLds[128];

    const int tid = threadIdx.x;
    if (tid < 128) {
        int gr = m0 + tid;
        tokLds[tid] = (gr < cn) ? tokslot[e * T_TOK + gr] : 0;
    }
    __syncthreads();

    const int lane = tid & 63;
    const int wave = tid >> 6;
    const int fm = lane & 15, quad = lane >> 4;

    const int srow = wave * 16 + (lane >> 2);
    const int scol = (lane & 3) * 8;
    int ar1 = m0 + srow;      if (ar1 >= cn) ar1 = cn - 1;
    int ar2 = m0 + 64 + srow; if (ar2 >= cn) ar2 = cn - 1;
    const unsigned short* aG1 = hbuf + (size_t)(off + ar1) * I_DIM + scol;
    const unsigned short* aG2 = hbuf + (size_t)(off + ar2) * I_DIM + scol;
    const unsigned short* bG1 = dbt + ((size_t)e * H_DIM + n0 + srow) * I_DIM + scol;
    const unsigned short* bG2 = dbt + ((size_t)e * H_DIM + n0 + 64 + srow) * I_DIM + scol;
    unsigned short* lA1 = ldsA + wave * 512;
    unsigned short* lA2 = ldsA + 2048 + wave * 512;
    unsigned short* lB1 = ldsB + wave * 512;
    unsigned short* lB2 = ldsB + 2048 + wave * 512;

    const int wm = (wave & 1) * 64, wn = (wave >> 1) * 64;

    v4f acc[4][4];
#pragma unroll
    for (int i = 0; i < 4; i++)
#pragma unroll
        for (int j = 0; j < 4; j++) acc[i][j] = (v4f)0.f;

    for (int kb = 0; kb < I_DIM / 32; kb++) {
        const int k0 = kb * 32;
        async16(aG1 + k0, lA1);
        async16(aG2 + k0, lA2);
        async16(bG1 + k0, lB1);
        async16(bG2 + k0, lB2);
        __syncthreads();
        v8s aF[4], bF[4];
#pragma unroll
        for (int im = 0; im < 4; im++)
            aF[im] = *(const v8s*)&ldsA[(wm + im * 16 + fm) * 32 + quad * 8];
#pragma unroll
        for (int in = 0; in < 4; in++)
            bF[in] = *(const v8s*)&ldsB[(wn + in * 16 + fm) * 32 + quad * 8];
#pragma unroll
        for (int im = 0; im < 4; im++)
#pragma unroll
            for (int in = 0; in < 4; in++)
                acc[im][in] = __builtin_amdgcn_mfma_f32_16x16x32_bf16(aF[im], bF[in], acc[im][in], 0, 0, 0);
        __syncthreads();
    }

#pragma unroll
    for (int im = 0; im < 4; im++) {
#pragma unroll
        for (int reg = 0; reg < 4; reg++) {
            int lr = wm + im * 16 + quad * 4 + reg;
            int gr = m0 + lr;
            if (gr < cn) {
                int tok = tokLds[lr];
#pragma unroll
                for (int in = 0; in < 4; in++) {
                    int col = n0 + wn + in * 16 + fm;
                    atomicAdd(&out[(size_t)tok * H_DIM + col], acc[im][in][reg]);
                }
            }
        }
    }
}

extern "C" void kernel_launch(void* const* d_in, const int* in_sizes, int n_in,
                              void* d_out, int out_size, void* d_ws, size_t ws_size,
                              hipStream_t stream) {
    const float* x  = (const float*)d_in[0];
    const float* rw = (const float*)d_in[1];
    const float* rb = (const float*)d_in[2];
    const float* gw = (const float*)d_in[3];
    const float* uw = (const float*)d_in[4];
    const float* dw = (const float*)d_in[5];
    float* out = (float*)d_out;

    char* ws = (char*)d_ws;
    size_t o = 0;
    auto alloc = [&](size_t bytes) { void* p = ws + o; o += (bytes + 255) & ~255ull; return p; };
    int*   cnt     = (int*)  alloc(N_EXP * 4);
    int*   tokslot = (int*)  alloc((size_t)N_EXP * T_TOK * 4);
    float* pweight = (float*)alloc((size_t)N_EXP * T_TOK * 4);
    int*   top2e   = (int*)  alloc((size_t)T_TOK * 4);
    float2* top2w  = (float2*)alloc((size_t)T_TOK * 8);
    unsigned short* xb   = (unsigned short*)alloc((size_t)T_TOK * H_DIM * 2);
    unsigned short* gbt  = (unsigned short*)alloc((size_t)N_EXP * H_DIM * I_DIM * 2);
    unsigned short* ubt  = (unsigned short*)alloc((size_t)N_EXP * H_DIM * I_DIM * 2);
    unsigned short* dbt  = (unsigned short*)alloc((size_t)N_EXP * H_DIM * I_DIM * 2);
    unsigned short* hbuf = (unsigned short*)alloc((size_t)2 * T_TOK * I_DIM * 2);

    hipMemsetAsync(cnt, 0, N_EXP * 4, stream);
    hipMemsetAsync(d_out, 0, (size_t)out_size * 4, stream);

    dim3 tg1(I_DIM / 32, H_DIM / 32, 2 * N_EXP);
    k_transp<<<tg1, dim3(32, 8), 0, stream>>>(gw, uw, gbt, ubt, H_DIM, I_DIM);
    dim3 tg2(H_DIM / 32, I_DIM / 32, N_EXP);
    k_transp<<<tg2, dim3(32, 8), 0, stream>>>(dw, dw, dbt, dbt, I_DIM, H_DIM);

    k_router_a<<<T_TOK / 4, 256, 0, stream>>>(x, rw, rb, xb, top2e, top2w);
    k_router_b<<<T_TOK / 256, 256, 0, stream>>>(top2e, top2w, cnt, tokslot, pweight);

    dim3 g1(T_TOK / 128, I_DIM / 64, N_EXP);
    k_gateup<<<g1, 256, 0, stream>>>(xb, gbt, ubt, cnt, tokslot, pweight, hbuf);

    dim3 g2(T_TOK / 128, H_DIM / 128, N_EXP);
    k_down<<<g2, 256, 0, stream>>>(hbuf, dbt, cnt, tokslot, out);
}

// Round 4
// 265.915 us; speedup vs baseline: 1.8981x; 1.0760x over previous
//
#include <hip/hip_runtime.h>
#include <hip/hip_bf16.h>
#include <cstdint>
#include <cstddef>

#define T_TOK 8192
#define H_DIM 768
#define I_DIM 1024
#define N_EXP 5
#define MAXTILE 136

typedef short v8s __attribute__((ext_vector_type(8)));
typedef float v4f __attribute__((ext_vector_type(4)));

static __device__ __forceinline__ unsigned short f2bf(float f) {
    union { float f; unsigned int u; } v; v.f = f;
    unsigned int u = v.u;
    unsigned int r = (u + 0x7fffu + ((u >> 16) & 1u)) >> 16;
    return (unsigned short)r;
}
static __device__ __forceinline__ float bf2f(unsigned short s) {
    union { unsigned int u; float f; } v; v.u = ((unsigned int)s) << 16; return v.f;
}

// async 16B global->LDS (wave-uniform LDS base + lane*16)
static __device__ __forceinline__ void async16(const unsigned short* g, unsigned short* l) {
    __builtin_amdgcn_global_load_lds(
        (const __attribute__((address_space(1))) unsigned int*)g,
        (__attribute__((address_space(3))) unsigned int*)l, 16, 0, 0);
}

// ---- gate/up transpose+convert+INTERLEAVE: [e][H][I] fp32 -> wbt[e][2I][H] bf16 ----
// gate col c -> row (c>>4)*32 + (c&15);  up col c -> row (c>>4)*32 + 16 + (c&15)
__global__ void k_transp_wi(const float* __restrict__ gw, const float* __restrict__ uw,
                            unsigned short* __restrict__ wbt) {
    __shared__ float tile[32][33];
    int z = blockIdx.z;
    int e = z % N_EXP;
    int isUp = z >= N_EXP;
    const float* src = (isUp ? uw : gw) + (size_t)e * H_DIM * I_DIM;
    int c0 = blockIdx.x * 32, r0 = blockIdx.y * 32;
    int tx = threadIdx.x, ty = threadIdx.y;
#pragma unroll
    for (int i = 0; i < 4; i++)
        tile[ty * 4 + i][tx] = src[(size_t)(r0 + ty * 4 + i) * I_DIM + c0 + tx];
    __syncthreads();
#pragma unroll
    for (int i = 0; i < 4; i++) {
        int c = c0 + ty * 4 + i;
        int row = (c >> 4) * 32 + (c & 15) + (isUp ? 16 : 0);
        wbt[((size_t)e * 2 * I_DIM + row) * H_DIM + r0 + tx] = f2bf(tile[tx][ty * 4 + i]);
    }
}

// ---- down transpose+convert: [e][I][H] fp32 -> dbt[e][H][I] bf16 ----
__global__ void k_transp_d(const float* __restrict__ dw, unsigned short* __restrict__ dbt) {
    __shared__ float tile[32][33];
    int e = blockIdx.z;
    const float* src = dw + (size_t)e * I_DIM * H_DIM;
    unsigned short* dst = dbt + (size_t)e * I_DIM * H_DIM;
    int c0 = blockIdx.x * 32, r0 = blockIdx.y * 32;
    int tx = threadIdx.x, ty = threadIdx.y;
#pragma unroll
    for (int i = 0; i < 4; i++)
        tile[ty * 4 + i][tx] = src[(size_t)(r0 + ty * 4 + i) * H_DIM + c0 + tx];
    __syncthreads();
#pragma unroll
    for (int i = 0; i < 4; i++)
        dst[(size_t)(c0 + ty * 4 + i) * I_DIM + r0 + tx] = f2bf(tile[tx][ty * 4 + i]);
}

// ---- router phase A: logits + top2 + fused x->bf16 convert ----
__global__ void k_router_a(const float* __restrict__ x, const float* __restrict__ rw,
                           const float* __restrict__ rb,
                           unsigned short* __restrict__ xb,
                           int* __restrict__ top2e, float2* __restrict__ top2w) {
    const int wave = threadIdx.x >> 6, lane = threadIdx.x & 63;
    const int t = blockIdx.x * 4 + wave;
    const float* xr = x + (size_t)t * H_DIM;
    unsigned short* xbr = xb + (size_t)t * H_DIM;
    float acc[N_EXP];
#pragma unroll
    for (int e = 0; e < N_EXP; e++) acc[e] = 0.f;
#pragma unroll
    for (int j = 0; j < H_DIM / 256; j++) {
        int idx = j * 256 + lane * 4;
        float4 xv = *(const float4*)(xr + idx);
        ushort4 o;
        o.x = f2bf(xv.x); o.y = f2bf(xv.y); o.z = f2bf(xv.z); o.w = f2bf(xv.w);
        *(ushort4*)(xbr + idx) = o;
#pragma unroll
        for (int e = 0; e < N_EXP; e++) {
            float4 wv = *(const float4*)(rw + e * H_DIM + idx);
            acc[e] += xv.x * wv.x + xv.y * wv.y + xv.z * wv.z + xv.w * wv.w;
        }
    }
#pragma unroll
    for (int s = 32; s > 0; s >>= 1) {
#pragma unroll
        for (int e = 0; e < N_EXP; e++) acc[e] += __shfl_down(acc[e], s);
    }
    if (lane == 0) {
        float l[N_EXP];
#pragma unroll
        for (int e = 0; e < N_EXP; e++) l[e] = acc[e] + rb[e];
        int i1 = 0;
#pragma unroll
        for (int e = 1; e < N_EXP; e++) if (l[e] > l[i1]) i1 = e;
        int i2 = (i1 == 0) ? 1 : 0;
#pragma unroll
        for (int e = 0; e < N_EXP; e++) if (e != i1 && l[e] > l[i2]) i2 = e;
        float w1 = 1.f / (1.f + __expf(l[i2] - l[i1]));
        top2e[t] = i1 | (i2 << 8);
        top2w[t] = make_float2(w1, 1.f - w1);
    }
}

// ---- router phase B: block-aggregated list build; slot bit in tokslot bit16 ----
__global__ void k_router_b(const int* __restrict__ top2e, const float2* __restrict__ top2w,
                           int* __restrict__ cnt, int* __restrict__ tokslot,
                           float* __restrict__ pweight) {
    __shared__ int lcnt[N_EXP], lbase[N_EXP];
    const int tid = threadIdx.x;
    if (tid < N_EXP) lcnt[tid] = 0;
    __syncthreads();
    const int t = blockIdx.x * 256 + tid;
    const int pe = top2e[t];
    const float2 wv = top2w[t];
    const int e1 = pe & 0xff, e2 = pe >> 8;
    const int s1 = atomicAdd(&lcnt[e1], 1);
    const int s2 = atomicAdd(&lcnt[e2], 1);
    __syncthreads();
    if (tid < N_EXP) lbase[tid] = atomicAdd(&cnt[tid], lcnt[tid]);
    __syncthreads();
    const int p1 = lbase[e1] + s1;
    tokslot[e1 * T_TOK + p1] = t; pweight[e1 * T_TOK + p1] = wv.x;
    const int p2 = lbase[e2] + s2;
    tokslot[e2 * T_TOK + p2] = t | (1 << 16); pweight[e2 * T_TOK + p2] = wv.y;
}

// ---- build compact tile list: (expert, m0, row_offset) ----
__global__ void k_tiles(const int* __restrict__ cnt, int4* __restrict__ tiles) {
    const int tid = threadIdx.x;
    if (tid < MAXTILE) tiles[tid] = make_int4(-1, 0, 0, 0);
    __syncthreads();
    if (tid == 0) {
        int off = 0, idx = 0;
        for (int e = 0; e < N_EXP; e++) {
            int cn = cnt[e];
            for (int m0 = 0; m0 < cn; m0 += 128)
                tiles[idx++] = make_int4(e, m0, off, cn);
            off += cn;
        }
    }
}

// ---- gate+up fused GEMM, m97 2x2-wave structure on interleaved wbt ----
__launch_bounds__(256, 2)
__global__ void k_gateup(const unsigned short* __restrict__ xb,
                         const unsigned short* __restrict__ wbt,
                         const int4* __restrict__ tiles,
                         const int* __restrict__ tokslot,
                         const float* __restrict__ pweight,
                         unsigned short* __restrict__ hbuf) {
    const int4 td = tiles[blockIdx.x];
    const int e = td.x;
    if (e < 0) return;
    const int m0 = td.y, offe = td.z, cn = td.w;
    const int n0 = blockIdx.y * 64;   // actual I columns [n0, n0+64)

    __shared__ __align__(16) unsigned short ldsA[128 * 32];
    __shared__ __align__(16) unsigned short ldsB[128 * 32];
    __shared__ int tokLds[128];
    __shared__ float pwLds[128];

    const int tid = threadIdx.x;
    if (tid < 128) {
        int gr = m0 + tid;
        int tk = 0; float pw = 0.f;
        if (gr < cn) { tk = tokslot[e * T_TOK + gr] & 0xFFFF; pw = pweight[e * T_TOK + gr]; }
        tokLds[tid] = tk; pwLds[tid] = pw;
    }
    __syncthreads();

    const int lane = tid & 63;
    const int wave = tid >> 6;
    const int fm = lane & 15, quad = lane >> 4;

    const int srow = wave * 16 + (lane >> 2);   // 0..63
    const int scol = (lane & 3) * 8;
    const unsigned short* aG1 = xb + (size_t)tokLds[srow] * H_DIM + scol;
    const unsigned short* aG2 = xb + (size_t)tokLds[64 + srow] * H_DIM + scol;
    const unsigned short* bG1 = wbt + ((size_t)e * 2 * I_DIM + n0 * 2 + srow) * H_DIM + scol;
    const unsigned short* bG2 = wbt + ((size_t)e * 2 * I_DIM + n0 * 2 + 64 + srow) * H_DIM + scol;
    unsigned short* lA1 = ldsA + wave * 512;
    unsigned short* lA2 = ldsA + 2048 + wave * 512;
    unsigned short* lB1 = ldsB + wave * 512;
    unsigned short* lB2 = ldsB + 2048 + wave * 512;

    const int wm = (wave & 1) * 64, wnw = wave >> 1;   // eff-rows wnw*64

    v4f acc[4][4];
#pragma unroll
    for (int i = 0; i < 4; i++)
#pragma unroll
        for (int j = 0; j < 4; j++) acc[i][j] = (v4f)0.f;

    for (int kb = 0; kb < H_DIM / 32; kb++) {
        const int k0 = kb * 32;
        async16(aG1 + k0, lA1);
        async16(aG2 + k0, lA2);
        async16(bG1 + k0, lB1);
        async16(bG2 + k0, lB2);
        __syncthreads();
        v8s aF[4], bF[4];
#pragma unroll
        for (int im = 0; im < 4; im++)
            aF[im] = *(const v8s*)&ldsA[(wm + im * 16 + fm) * 32 + quad * 8];
#pragma unroll
        for (int in = 0; in < 4; in++)
            bF[in] = *(const v8s*)&ldsB[(wnw * 64 + in * 16 + fm) * 32 + quad * 8];
#pragma unroll
        for (int im = 0; im < 4; im++)
#pragma unroll
            for (int in = 0; in < 4; in++)
                acc[im][in] = __builtin_amdgcn_mfma_f32_16x16x32_bf16(aF[im], bF[in], acc[im][in], 0, 0, 0);
        __syncthreads();
    }

    // acc[im][2j] = gate, acc[im][2j+1] = up, same actual cols n0 + wnw*32 + j*16 + fm
#pragma unroll
    for (int im = 0; im < 4; im++) {
#pragma unroll
        for (int reg = 0; reg < 4; reg++) {
            int lr = wm + im * 16 + quad * 4 + reg;
            int gr = m0 + lr;
            if (gr < cn) {
                float pw = pwLds[lr];
                size_t base = (size_t)(offe + gr) * I_DIM + n0 + wnw * 32 + fm;
#pragma unroll
                for (int j = 0; j < 2; j++) {
                    float g = acc[im][2 * j][reg];
                    float u = acc[im][2 * j + 1][reg];
                    float s = g / (1.f + __expf(-g));
                    hbuf[base + j * 16] = f2bf(s * u * pw);
                }
            }
        }
    }
}

// ---- down GEMM (m97 128x128), plain bf16 stores into ybuf[slot][tok][H] ----
__launch_bounds__(256, 2)
__global__ void k_down(const unsigned short* __restrict__ hbuf,
                       const unsigned short* __restrict__ dbt,
                       const int4* __restrict__ tiles,
                       const int* __restrict__ tokslot,
                       unsigned short* __restrict__ ybuf) {
    const int4 td = tiles[blockIdx.x];
    const int e = td.x;
    if (e < 0) return;
    const int m0 = td.y, offe = td.z, cn = td.w;
    const int n0 = blockIdx.y * 128;

    __shared__ __align__(16) unsigned short ldsA[128 * 32];
    __shared__ __align__(16) unsigned short ldsB[128 * 32];
    __shared__ int tokLds[128];

    const int tid = threadIdx.x;
    if (tid < 128) {
        int gr = m0 + tid;
        tokLds[tid] = (gr < cn) ? tokslot[e * T_TOK + gr] : 0;
    }
    __syncthreads();

    const int lane = tid & 63;
    const int wave = tid >> 6;
    const int fm = lane & 15, quad = lane >> 4;

    const int srow = wave * 16 + (lane >> 2);
    const int scol = (lane & 3) * 8;
    int ar1 = m0 + srow;      if (ar1 >= cn) ar1 = cn - 1;
    int ar2 = m0 + 64 + srow; if (ar2 >= cn) ar2 = cn - 1;
    const unsigned short* aG1 = hbuf + (size_t)(offe + ar1) * I_DIM + scol;
    const unsigned short* aG2 = hbuf + (size_t)(offe + ar2) * I_DIM + scol;
    const unsigned short* bG1 = dbt + ((size_t)e * H_DIM + n0 + srow) * I_DIM + scol;
    const unsigned short* bG2 = dbt + ((size_t)e * H_DIM + n0 + 64 + srow) * I_DIM + scol;
    unsigned short* lA1 = ldsA + wave * 512;
    unsigned short* lA2 = ldsA + 2048 + wave * 512;
    unsigned short* lB1 = ldsB + wave * 512;
    unsigned short* lB2 = ldsB + 2048 + wave * 512;

    const int wm = (wave & 1) * 64, wn = (wave >> 1) * 64;

    v4f acc[4][4];
#pragma unroll
    for (int i = 0; i < 4; i++)
#pragma unroll
        for (int j = 0; j < 4; j++) acc[i][j] = (v4f)0.f;

    for (int kb = 0; kb < I_DIM / 32; kb++) {
        const int k0 = kb * 32;
        async16(aG1 + k0, lA1);
        async16(aG2 + k0, lA2);
        async16(bG1 + k0, lB1);
        async16(bG2 + k0, lB2);
        __syncthreads();
        v8s aF[4], bF[4];
#pragma unroll
        for (int im = 0; im < 4; im++)
            aF[im] = *(const v8s*)&ldsA[(wm + im * 16 + fm) * 32 + quad * 8];
#pragma unroll
        for (int in = 0; in < 4; in++)
            bF[in] = *(const v8s*)&ldsB[(wn + in * 16 + fm) * 32 + quad * 8];
#pragma unroll
        for (int im = 0; im < 4; im++)
#pragma unroll
            for (int in = 0; in < 4; in++)
                acc[im][in] = __builtin_amdgcn_mfma_f32_16x16x32_bf16(aF[im], bF[in], acc[im][in], 0, 0, 0);
        __syncthreads();
    }

#pragma unroll
    for (int im = 0; im < 4; im++) {
#pragma unroll
        for (int reg = 0; reg < 4; reg++) {
            int lr = wm + im * 16 + quad * 4 + reg;
            int gr = m0 + lr;
            if (gr < cn) {
                int v = tokLds[lr];
                int tok = v & 0xFFFF, s = (v >> 16) & 1;
#pragma unroll
                for (int in = 0; in < 4; in++) {
                    int col = n0 + wn + in * 16 + fm;
                    ybuf[((size_t)s * T_TOK + tok) * H_DIM + col] = f2bf(acc[im][in][reg]);
                }
            }
        }
    }
}

// ---- combine: out = ybuf[0] + ybuf[1], fp32 out ----
__global__ void k_combine(const unsigned short* __restrict__ ybuf, float* __restrict__ out) {
    const size_t i8 = ((size_t)blockIdx.x * 256 + threadIdx.x) * 8;
    const unsigned short* y0 = ybuf + i8;
    const unsigned short* y1 = ybuf + (size_t)T_TOK * H_DIM + i8;
    ushort4 a0 = *(const ushort4*)y0, a1 = *(const ushort4*)(y0 + 4);
    ushort4 b0 = *(const ushort4*)y1, b1 = *(const ushort4*)(y1 + 4);
    float4 o0, o1;
    o0.x = bf2f(a0.x) + bf2f(b0.x); o0.y = bf2f(a0.y) + bf2f(b0.y);
    o0.z = bf2f(a0.z) + bf2f(b0.z); o0.w = bf2f(a0.w) + bf2f(b0.w);
    o1.x = bf2f(a1.x) + bf2f(b1.x); o1.y = bf2f(a1.y) + bf2f(b1.y);
    o1.z = bf2f(a1.z) + bf2f(b1.z); o1.w = bf2f(a1.w) + bf2f(b1.w);
    *(float4*)(out + i8) = o0;
    *(float4*)(out + i8 + 4) = o1;
}

extern "C" void kernel_launch(void* const* d_in, const int* in_sizes, int n_in,
                              void* d_out, int out_size, void* d_ws, size_t ws_size,
                              hipStream_t stream) {
    const float* x  = (const float*)d_in[0];
    const float* rw = (const float*)d_in[1];
    const float* rb = (const float*)d_in[2];
    const float* gw = (const float*)d_in[3];
    const float* uw = (const float*)d_in[4];
    const float* dw = (const float*)d_in[5];
    float* out = (float*)d_out;

    char* ws = (char*)d_ws;
    size_t o = 0;
    auto alloc = [&](size_t bytes) { void* p = ws + o; o += (bytes + 255) & ~255ull; return p; };
    int*   cnt     = (int*)  alloc(N_EXP * 4);
    int*   tokslot = (int*)  alloc((size_t)N_EXP * T_TOK * 4);
    float* pweight = (float*)alloc((size_t)N_EXP * T_TOK * 4);
    int*   top2e   = (int*)  alloc((size_t)T_TOK * 4);
    float2* top2w  = (float2*)alloc((size_t)T_TOK * 8);
    int4*  tiles   = (int4*) alloc((size_t)MAXTILE * 16);
    unsigned short* xb   = (unsigned short*)alloc((size_t)T_TOK * H_DIM * 2);
    unsigned short* wbt  = (unsigned short*)alloc((size_t)N_EXP * 2 * I_DIM * H_DIM * 2);
    unsigned short* dbt  = (unsigned short*)alloc((size_t)N_EXP * H_DIM * I_DIM * 2);
    unsigned short* hbuf = (unsigned short*)alloc((size_t)2 * T_TOK * I_DIM * 2);
    unsigned short* ybuf = (unsigned short*)alloc((size_t)2 * T_TOK * H_DIM * 2);

    hipMemsetAsync(cnt, 0, N_EXP * 4, stream);

    dim3 tg1(I_DIM / 32, H_DIM / 32, 2 * N_EXP);
    k_transp_wi<<<tg1, dim3(32, 8), 0, stream>>>(gw, uw, wbt);
    dim3 tg2(H_DIM / 32, I_DIM / 32, N_EXP);
    k_transp_d<<<tg2, dim3(32, 8), 0, stream>>>(dw, dbt);

    k_router_a<<<T_TOK / 4, 256, 0, stream>>>(x, rw, rb, xb, top2e, top2w);
    k_router_b<<<T_TOK / 256, 256, 0, stream>>>(top2e, top2w, cnt, tokslot, pweight);
    k_tiles<<<1, 256, 0, stream>>>(cnt, tiles);

    dim3 g1(MAXTILE, I_DIM / 64);
    k_gateup<<<g1, 256, 0, stream>>>(xb, wbt, tiles, tokslot, pweight, hbuf);

    dim3 g2(MAXTILE, H_DIM / 128);
    k_down<<<g2, 256, 0, stream>>>(hbuf, dbt, tiles, tokslot, ybuf);

    k_combine<<<(T_TOK * H_DIM) / (256 * 8), 256, 0, stream>>>(ybuf, out);
}